// Round 1
// baseline (4772.625 us; speedup 1.0000x reference)
//
#include <hip/hip_runtime.h>
#include <hip/hip_fp16.h>

typedef unsigned int u32;
typedef _Float16 half2_t __attribute__((ext_vector_type(2)));

// ---- constants (B=64, T=1024, D=H=256) ----
#define NB   64
#define NT   1024
#define NH   256
#define G3   768          // 3*H
#define NK2  128          // K/2 packed f16 pairs
#define WPACK_ELEMS 98304 // NK2 * G3 per direction

static __device__ __forceinline__ float fdot2f(u32 a, u32 b, float c) {
#if __has_builtin(__builtin_amdgcn_fdot2)
    return __builtin_amdgcn_fdot2(__builtin_bit_cast(half2_t, a),
                                  __builtin_bit_cast(half2_t, b), c, false);
#else
    half2_t av = __builtin_bit_cast(half2_t, a);
    half2_t bv = __builtin_bit_cast(half2_t, b);
    c = fmaf((float)av[0], (float)bv[0], c);
    c = fmaf((float)av[1], (float)bv[1], c);
    return c;
#endif
}

static __device__ __forceinline__ u32 packh2(float lo, float hi) {
    half2_t v;
    v[0] = (_Float16)lo;
    v[1] = (_Float16)hi;
    return __builtin_bit_cast(u32, v);
}

static __device__ __forceinline__ float sigmoidf_fast(float x) {
    return 1.0f / (1.0f + __expf(-x));
}
static __device__ __forceinline__ float tanhf_fast(float x) {
    return 2.0f / (1.0f + __expf(-2.0f * x)) - 1.0f;
}

// Pack a (768,256) fp32 weight matrix (both directions) into f16-pair stream
// layout: dst[dir][k2][g] = half2(w[g][2k2], w[g][2k2+1]), g = gate*256 + j.
__global__ void pack_w(const float* __restrict__ src_fw,
                       const float* __restrict__ src_bw,
                       u32* __restrict__ dst) {
    int id = blockIdx.x * 256 + threadIdx.x;   // [0, 2*98304)
    int dir = id >= WPACK_ELEMS;
    int r   = id - dir * WPACK_ELEMS;          // [0, 98304)
    int j    = r & 255;
    int q    = r >> 8;                         // [0, 384)
    int gate = q % 3;
    int k2   = q / 3;
    const float* src = dir ? src_bw : src_fw;
    int g = gate * 256 + j;
    float lo = src[g * 256 + 2 * k2];
    float hi = src[g * 256 + 2 * k2 + 1];
    dst[dir * WPACK_ELEMS + k2 * G3 + g] = packh2(lo, hi);
}

// gates_x GEMM: gx[dir][m][g] = sum_k x[m][k]*w_ih[dir][g][k] + b_ih[dir][g]
// One block: 16 m-rows x all 768 g. Thread j owns (r,z,n) for hidden j.
__global__ __launch_bounds__(256) void gemm_gx(
        const float* __restrict__ x, const u32* __restrict__ wihp,
        const float* __restrict__ bih_fw, const float* __restrict__ bih_bw,
        _Float16* __restrict__ gx) {
    int dir = blockIdx.y;
    int m0  = blockIdx.x * 16;
    int j   = threadIdx.x;

    __shared__ u32 xs[16][NK2];
    #pragma unroll
    for (int rep = 0; rep < 8; ++rep) {
        int lin = rep * 256 + j;       // [0, 2048)
        int mi  = lin >> 7;
        int k2  = lin & 127;
        const float* xr = x + (size_t)(m0 + mi) * 256 + 2 * k2;
        xs[mi][k2] = packh2(xr[0], xr[1]);
    }
    __syncthreads();

    const u32* wp = wihp + dir * WPACK_ELEMS;
    const float* bih = dir ? bih_bw : bih_fw;

    float accr[16], accz[16], accn[16];
    #pragma unroll
    for (int mi = 0; mi < 16; ++mi) { accr[mi] = 0.f; accz[mi] = 0.f; accn[mi] = 0.f; }

    #pragma unroll 2
    for (int k2 = 0; k2 < NK2; ++k2) {
        u32 wr = wp[k2 * G3 + j];
        u32 wz = wp[k2 * G3 + 256 + j];
        u32 wn = wp[k2 * G3 + 512 + j];
        #pragma unroll
        for (int mi = 0; mi < 16; ++mi) {
            u32 xv = xs[mi][k2];
            accr[mi] = fdot2f(xv, wr, accr[mi]);
            accz[mi] = fdot2f(xv, wz, accz[mi]);
            accn[mi] = fdot2f(xv, wn, accn[mi]);
        }
    }

    float br = bih[j], bz = bih[256 + j], bn = bih[512 + j];
    _Float16* gxd = gx + (size_t)dir * 65536 * G3;
    #pragma unroll
    for (int mi = 0; mi < 16; ++mi) {
        size_t row = (size_t)(m0 + mi) * G3;
        gxd[row + j]       = (_Float16)(accr[mi] + br);
        gxd[row + 256 + j] = (_Float16)(accz[mi] + bz);
        gxd[row + 512 + j] = (_Float16)(accn[mi] + bn);
    }
}

// Recurrence: one block per (batch, direction) chain. Thread j owns hidden j.
__global__ __launch_bounds__(256) void gru_rec(
        const _Float16* __restrict__ gx, const u32* __restrict__ whhp,
        const float* __restrict__ bhh_fw, const float* __restrict__ bhh_bw,
        float* __restrict__ out) {
    int b   = blockIdx.x;
    int dir = blockIdx.y;
    int j   = threadIdx.x;

    __shared__ u32 hl[2][NK2];   // double-buffered h as f16 pairs

    const u32* wp = whhp + dir * WPACK_ELEMS;
    const float* bhh = dir ? bhh_bw : bhh_fw;
    float bhr = bhh[j], bhz = bhh[256 + j], bhn = bhh[512 + j];

    const _Float16* gxp = gx + ((size_t)dir * NB + b) * NT * G3;

    float h = 0.0f;
    ((_Float16*)hl)[j] = (_Float16)0.0f;   // zero buffer 0 (256 halves = 128 u32)
    __syncthreads();

    int cur = 0;
    for (int tt = 0; tt < NT; ++tt) {
        int t = dir ? (NT - 1 - tt) : tt;
        const _Float16* gxt = gxp + (size_t)t * G3;
        float gxr = (float)gxt[j];
        float gxz = (float)gxt[256 + j];
        float gxn = (float)gxt[512 + j];

        float ar = 0.f, az = 0.f, an = 0.f;
        const u32* hp = hl[cur];
        #pragma unroll 8
        for (int k2 = 0; k2 < NK2; ++k2) {
            u32 hv = hp[k2];
            ar = fdot2f(hv, wp[k2 * G3 + j],       ar);
            az = fdot2f(hv, wp[k2 * G3 + 256 + j], az);
            an = fdot2f(hv, wp[k2 * G3 + 512 + j], an);
        }

        float r = sigmoidf_fast(gxr + ar + bhr);
        float z = sigmoidf_fast(gxz + az + bhz);
        float n = tanhf_fast(gxn + r * (an + bhn));
        h = z * h + (1.0f - z) * n;

        out[((size_t)b * NT + t) * 512 + dir * 256 + j] = h;
        ((_Float16*)hl[cur ^ 1])[j] = (_Float16)h;
        __syncthreads();
        cur ^= 1;
    }

    // final hidden states: h_fw then h_bw after the big outputs block
    float* hout = out + (size_t)NB * NT * 512 + dir * (NB * NH);
    hout[b * NH + j] = h;
}

extern "C" void kernel_launch(void* const* d_in, const int* in_sizes, int n_in,
                              void* d_out, int out_size, void* d_ws, size_t ws_size,
                              hipStream_t stream) {
    const float* x      = (const float*)d_in[0];
    const float* wih_fw = (const float*)d_in[1];
    const float* whh_fw = (const float*)d_in[2];
    const float* bih_fw = (const float*)d_in[3];
    const float* bhh_fw = (const float*)d_in[4];
    const float* wih_bw = (const float*)d_in[5];
    const float* whh_bw = (const float*)d_in[6];
    const float* bih_bw = (const float*)d_in[7];
    const float* bhh_bw = (const float*)d_in[8];
    float* out = (float*)d_out;

    char* ws = (char*)d_ws;
    _Float16* gx = (_Float16*)ws;                      // 2*65536*768*2 = 201,326,592 B
    u32* wihp = (u32*)(ws + 201326592);                // 786,432 B
    u32* whhp = (u32*)(ws + 202113024);                // 786,432 B

    pack_w<<<768, 256, 0, stream>>>(wih_fw, wih_bw, wihp);
    pack_w<<<768, 256, 0, stream>>>(whh_fw, whh_bw, whhp);
    gemm_gx<<<dim3(4096, 2), 256, 0, stream>>>(x, wihp, bih_fw, bih_bw, gx);
    gru_rec<<<dim3(NB, 2), 256, 0, stream>>>(gx, whhp, bhh_fw, bhh_bw, out);
}

// Round 2
// 3777.891 us; speedup vs baseline: 1.2633x; 1.2633x over previous
//
#include <hip/hip_runtime.h>
#include <hip/hip_fp16.h>

typedef unsigned int u32;
typedef _Float16 half2_t __attribute__((ext_vector_type(2)));
typedef u32 u32x4 __attribute__((ext_vector_type(4)));

// ---- constants (B=64, T=1024, D=H=256) ----
#define NB   64
#define NT   1024
#define NH   256
#define G3   768          // 3*H
#define NK2  128          // K/2 packed f16 pairs
#define WPACK_ELEMS 98304 // NK2 * G3 per direction

static __device__ __forceinline__ float fdot2f(u32 a, u32 b, float c) {
#if __has_builtin(__builtin_amdgcn_fdot2)
    return __builtin_amdgcn_fdot2(__builtin_bit_cast(half2_t, a),
                                  __builtin_bit_cast(half2_t, b), c, false);
#else
    half2_t av = __builtin_bit_cast(half2_t, a);
    half2_t bv = __builtin_bit_cast(half2_t, b);
    c = fmaf((float)av[0], (float)bv[0], c);
    c = fmaf((float)av[1], (float)bv[1], c);
    return c;
#endif
}

static __device__ __forceinline__ u32 packh2(float lo, float hi) {
    half2_t v;
    v[0] = (_Float16)lo;
    v[1] = (_Float16)hi;
    return __builtin_bit_cast(u32, v);
}

static __device__ __forceinline__ float sigmoidf_fast(float x) {
    return 1.0f / (1.0f + __expf(-x));
}
static __device__ __forceinline__ float tanhf_fast(float x) {
    return 2.0f / (1.0f + __expf(-2.0f * x)) - 1.0f;
}

// Pack a (768,256) fp32 weight matrix (both directions) into f16-pair stream
// layout: dst[dir][k2][g] = half2(w[g][2k2], w[g][2k2+1]), g = gate*256 + j.
__global__ void pack_w(const float* __restrict__ src_fw,
                       const float* __restrict__ src_bw,
                       u32* __restrict__ dst) {
    int id = blockIdx.x * 256 + threadIdx.x;   // [0, 2*98304)
    int dir = id >= WPACK_ELEMS;
    int r   = id - dir * WPACK_ELEMS;          // [0, 98304)
    int j    = r & 255;
    int q    = r >> 8;                         // [0, 384)
    int gate = q % 3;
    int k2   = q / 3;
    const float* src = dir ? src_bw : src_fw;
    int g = gate * 256 + j;
    float lo = src[g * 256 + 2 * k2];
    float hi = src[g * 256 + 2 * k2 + 1];
    dst[dir * WPACK_ELEMS + k2 * G3 + g] = packh2(lo, hi);
}

// gates_x GEMM: gx[dir][m][g] = sum_k x[m][k]*w_ih[dir][g][k] + b_ih[dir][g]
__global__ __launch_bounds__(256) void gemm_gx(
        const float* __restrict__ x, const u32* __restrict__ wihp,
        const float* __restrict__ bih_fw, const float* __restrict__ bih_bw,
        _Float16* __restrict__ gx) {
    int dir = blockIdx.y;
    int m0  = blockIdx.x * 16;
    int j   = threadIdx.x;

    __shared__ u32 xs[16][NK2];
    #pragma unroll
    for (int rep = 0; rep < 8; ++rep) {
        int lin = rep * 256 + j;       // [0, 2048)
        int mi  = lin >> 7;
        int k2  = lin & 127;
        const float* xr = x + (size_t)(m0 + mi) * 256 + 2 * k2;
        xs[mi][k2] = packh2(xr[0], xr[1]);
    }
    __syncthreads();

    const u32* wp = wihp + dir * WPACK_ELEMS;
    const float* bih = dir ? bih_bw : bih_fw;

    float accr[16], accz[16], accn[16];
    #pragma unroll
    for (int mi = 0; mi < 16; ++mi) { accr[mi] = 0.f; accz[mi] = 0.f; accn[mi] = 0.f; }

    #pragma unroll 2
    for (int k2 = 0; k2 < NK2; ++k2) {
        u32 wr = wp[k2 * G3 + j];
        u32 wz = wp[k2 * G3 + 256 + j];
        u32 wn = wp[k2 * G3 + 512 + j];
        #pragma unroll
        for (int mi = 0; mi < 16; ++mi) {
            u32 xv = xs[mi][k2];
            accr[mi] = fdot2f(xv, wr, accr[mi]);
            accz[mi] = fdot2f(xv, wz, accz[mi]);
            accn[mi] = fdot2f(xv, wn, accn[mi]);
        }
    }

    float br = bih[j], bz = bih[256 + j], bn = bih[512 + j];
    _Float16* gxd = gx + (size_t)dir * 65536 * G3;
    #pragma unroll
    for (int mi = 0; mi < 16; ++mi) {
        size_t row = (size_t)(m0 + mi) * G3;
        gxd[row + j]       = (_Float16)(accr[mi] + br);
        gxd[row + 256 + j] = (_Float16)(accz[mi] + bz);
        gxd[row + 512 + j] = (_Float16)(accn[mi] + bn);
    }
}

// Recurrence: one block per (batch, direction) chain. Thread j owns hidden j.
// w_hh is REGISTER-RESIDENT: 384 packed-f16 u32 per thread (thread j holds
// rows j, 256+j, 512+j of w_hh). Zero per-step weight traffic; h broadcast
// via double-buffered LDS with raw s_barrier (no vmcnt drain).
__global__ __launch_bounds__(256, 1) void gru_rec(
        const _Float16* __restrict__ gx, const u32* __restrict__ whhp,
        const float* __restrict__ bhh_fw, const float* __restrict__ bhh_bw,
        float* __restrict__ out) {
    int b   = blockIdx.x;
    int dir = blockIdx.y;
    int j   = threadIdx.x;

    __shared__ u32x4 hl[2][32];   // double-buffered h as packed f16 pairs

    const u32* wp = whhp + dir * WPACK_ELEMS;

    u32 wr[NK2], wz[NK2], wn[NK2];
    #pragma unroll
    for (int k2 = 0; k2 < NK2; ++k2) {
        wr[k2] = wp[k2 * G3 + j];
        wz[k2] = wp[k2 * G3 + 256 + j];
        wn[k2] = wp[k2 * G3 + 512 + j];
    }

    const float* bhh = dir ? bhh_bw : bhh_fw;
    float bhr = bhh[j], bhz = bhh[256 + j], bhn = bhh[512 + j];

    const _Float16* gxp = gx + ((size_t)dir * NB + b) * NT * G3;
    float* outp = out + (size_t)b * NT * 512 + dir * 256 + j;

    float h = 0.0f;
    ((_Float16*)hl)[j] = (_Float16)0.0f;   // zero buffer 0
    asm volatile("s_waitcnt lgkmcnt(0)" ::: "memory");
    __builtin_amdgcn_s_barrier();
    asm volatile("" ::: "memory");

    int cur = 0;
    const int tstep = dir ? -1 : 1;
    int t = dir ? (NT - 1) : 0;
    for (int tt = 0; tt < NT; ++tt, t += tstep) {
        const _Float16* gxt = gxp + (size_t)t * G3;
        float gxr = (float)gxt[j];
        float gxz = (float)gxt[256 + j];
        float gxn = (float)gxt[512 + j];

        float ar = 0.f, az = 0.f, an = 0.f;
        const u32x4* hp = hl[cur];
        #pragma unroll
        for (int k4 = 0; k4 < 32; ++k4) {
            u32x4 hv = hp[k4];   // wave-uniform address -> LDS broadcast
            #pragma unroll
            for (int e = 0; e < 4; ++e) {
                int k2 = k4 * 4 + e;
                ar = fdot2f(hv[e], wr[k2], ar);
                az = fdot2f(hv[e], wz[k2], az);
                an = fdot2f(hv[e], wn[k2], an);
            }
        }

        float r = sigmoidf_fast(gxr + ar + bhr);
        float z = sigmoidf_fast(gxz + az + bhz);
        float n = tanhf_fast(gxn + r * (an + bhn));
        h = z * h + (1.0f - z) * n;

        outp[(size_t)t * 512] = h;
        ((_Float16*)hl[cur ^ 1])[j] = (_Float16)h;
        asm volatile("s_waitcnt lgkmcnt(0)" ::: "memory");
        __builtin_amdgcn_s_barrier();
        asm volatile("" ::: "memory");
        cur ^= 1;
    }

    float* hout = out + (size_t)NB * NT * 512 + dir * (NB * NH);
    hout[b * NH + j] = h;
}

extern "C" void kernel_launch(void* const* d_in, const int* in_sizes, int n_in,
                              void* d_out, int out_size, void* d_ws, size_t ws_size,
                              hipStream_t stream) {
    const float* x      = (const float*)d_in[0];
    const float* wih_fw = (const float*)d_in[1];
    const float* whh_fw = (const float*)d_in[2];
    const float* bih_fw = (const float*)d_in[3];
    const float* bhh_fw = (const float*)d_in[4];
    const float* wih_bw = (const float*)d_in[5];
    const float* whh_bw = (const float*)d_in[6];
    const float* bih_bw = (const float*)d_in[7];
    const float* bhh_bw = (const float*)d_in[8];
    float* out = (float*)d_out;

    char* ws = (char*)d_ws;
    _Float16* gx = (_Float16*)ws;                      // 2*65536*768*2 = 201,326,592 B
    u32* wihp = (u32*)(ws + 201326592);                // 786,432 B
    u32* whhp = (u32*)(ws + 202113024);                // 786,432 B

    pack_w<<<768, 256, 0, stream>>>(wih_fw, wih_bw, wihp);
    pack_w<<<768, 256, 0, stream>>>(whh_fw, whh_bw, whhp);
    gemm_gx<<<dim3(4096, 2), 256, 0, stream>>>(x, wihp, bih_fw, bih_bw, gx);
    gru_rec<<<dim3(NB, 2), 256, 0, stream>>>(gx, whhp, bhh_fw, bhh_bw, out);
}

// Round 3
// 1546.388 us; speedup vs baseline: 3.0863x; 2.4430x over previous
//
#include <hip/hip_runtime.h>
#include <hip/hip_fp16.h>

typedef unsigned int u32;
typedef _Float16 half2_t __attribute__((ext_vector_type(2)));
typedef u32 u32x4 __attribute__((ext_vector_type(4)));

// ---- constants (B=64, T=1024, D=H=256) ----
#define NB   64
#define NT   1024
#define NH   256
#define G3   768          // 3*H
#define NK2  128          // K/2 packed f16 pairs
#define WPACK_ELEMS 98304 // NK2 * G3 per direction
#define KSPLIT 4
#define KPER   32         // k2 values per thread (NK2 / KSPLIT)

static __device__ __forceinline__ float fdot2f(u32 a, u32 b, float c) {
#if __has_builtin(__builtin_amdgcn_fdot2)
    return __builtin_amdgcn_fdot2(__builtin_bit_cast(half2_t, a),
                                  __builtin_bit_cast(half2_t, b), c, false);
#else
    half2_t av = __builtin_bit_cast(half2_t, a);
    half2_t bv = __builtin_bit_cast(half2_t, b);
    c = fmaf((float)av[0], (float)bv[0], c);
    c = fmaf((float)av[1], (float)bv[1], c);
    return c;
#endif
}

static __device__ __forceinline__ u32 packh2(float lo, float hi) {
    half2_t v;
    v[0] = (_Float16)lo;
    v[1] = (_Float16)hi;
    return __builtin_bit_cast(u32, v);
}

static __device__ __forceinline__ float sigmoidf_fast(float x) {
    return 1.0f / (1.0f + __expf(-x));
}
static __device__ __forceinline__ float tanhf_fast(float x) {
    return 2.0f / (1.0f + __expf(-2.0f * x)) - 1.0f;
}

// Pack a (768,256) fp32 weight matrix (both directions) into f16-pair stream
// layout: dst[dir][k2][g] = half2(w[g][2k2], w[g][2k2+1]), g = gate*256 + j.
__global__ void pack_w(const float* __restrict__ src_fw,
                       const float* __restrict__ src_bw,
                       u32* __restrict__ dst) {
    int id = blockIdx.x * 256 + threadIdx.x;   // [0, 2*98304)
    int dir = id >= WPACK_ELEMS;
    int r   = id - dir * WPACK_ELEMS;          // [0, 98304)
    int j    = r & 255;
    int q    = r >> 8;                         // [0, 384)
    int gate = q % 3;
    int k2   = q / 3;
    const float* src = dir ? src_bw : src_fw;
    int g = gate * 256 + j;
    float lo = src[g * 256 + 2 * k2];
    float hi = src[g * 256 + 2 * k2 + 1];
    dst[dir * WPACK_ELEMS + k2 * G3 + g] = packh2(lo, hi);
}

// gates_x GEMM: gx[dir][m][g] = sum_k x[m][k]*w_ih[dir][g][k] + b_ih[dir][g]
__global__ __launch_bounds__(256) void gemm_gx(
        const float* __restrict__ x, const u32* __restrict__ wihp,
        const float* __restrict__ bih_fw, const float* __restrict__ bih_bw,
        _Float16* __restrict__ gx) {
    int dir = blockIdx.y;
    int m0  = blockIdx.x * 16;
    int j   = threadIdx.x;

    __shared__ u32 xs[16][NK2];
    #pragma unroll
    for (int rep = 0; rep < 8; ++rep) {
        int lin = rep * 256 + j;       // [0, 2048)
        int mi  = lin >> 7;
        int k2  = lin & 127;
        const float* xr = x + (size_t)(m0 + mi) * 256 + 2 * k2;
        xs[mi][k2] = packh2(xr[0], xr[1]);
    }
    __syncthreads();

    const u32* wp = wihp + dir * WPACK_ELEMS;
    const float* bih = dir ? bih_bw : bih_fw;

    float accr[16], accz[16], accn[16];
    #pragma unroll
    for (int mi = 0; mi < 16; ++mi) { accr[mi] = 0.f; accz[mi] = 0.f; accn[mi] = 0.f; }

    #pragma unroll 2
    for (int k2 = 0; k2 < NK2; ++k2) {
        u32 wr = wp[k2 * G3 + j];
        u32 wz = wp[k2 * G3 + 256 + j];
        u32 wn = wp[k2 * G3 + 512 + j];
        #pragma unroll
        for (int mi = 0; mi < 16; ++mi) {
            u32 xv = xs[mi][k2];
            accr[mi] = fdot2f(xv, wr, accr[mi]);
            accz[mi] = fdot2f(xv, wz, accz[mi]);
            accn[mi] = fdot2f(xv, wn, accn[mi]);
        }
    }

    float br = bih[j], bz = bih[256 + j], bn = bih[512 + j];
    _Float16* gxd = gx + (size_t)dir * 65536 * G3;
    #pragma unroll
    for (int mi = 0; mi < 16; ++mi) {
        size_t row = (size_t)(m0 + mi) * G3;
        gxd[row + j]       = (_Float16)(accr[mi] + br);
        gxd[row + 256 + j] = (_Float16)(accz[mi] + bz);
        gxd[row + 512 + j] = (_Float16)(accn[mi] + bn);
    }
}

// Recurrence: one block per (batch, direction) chain, 1024 threads (16 waves).
// Thread (q = tid>>8, j = tid&255) holds w_hh rows {j, 256+j, 512+j} for
// k2 in [32q, 32q+32) -> 96 weight VGPRs per thread, guaranteed no spill.
// Per step: partial fdot2 sums -> LDS -> q==0 threads combine + gates.
__global__ __launch_bounds__(1024, 1) void gru_rec(
        const _Float16* __restrict__ gx, const u32* __restrict__ whhp,
        const float* __restrict__ bhh_fw, const float* __restrict__ bhh_bw,
        float* __restrict__ out) {
    int b   = blockIdx.x;
    int dir = blockIdx.y;
    int tid = threadIdx.x;
    int j   = tid & 255;
    int q   = tid >> 8;          // wave-uniform (wave 0..3 -> q=0, etc.)

    __shared__ u32x4 hl[2][32];          // double-buffered h as packed f16 pairs
    __shared__ float psum[KSPLIT][G3];   // 12 KB partial sums

    const u32* wp = whhp + dir * WPACK_ELEMS;

    u32 wr[KPER], wz[KPER], wn[KPER];
    #pragma unroll
    for (int k = 0; k < KPER; ++k) {
        int k2 = q * KPER + k;
        wr[k] = wp[k2 * G3 + j];
        wz[k] = wp[k2 * G3 + 256 + j];
        wn[k] = wp[k2 * G3 + 512 + j];
    }

    const float* bhh = dir ? bhh_bw : bhh_fw;
    float bhr = bhh[j], bhz = bhh[256 + j], bhn = bhh[512 + j];

    const _Float16* gxp = gx + ((size_t)dir * NB + b) * NT * G3;
    float* outp = out + (size_t)b * NT * 512 + dir * 256 + j;

    float h = 0.0f;
    if (tid < 256) ((_Float16*)hl)[tid] = (_Float16)0.0f;   // zero buffer 0
    __syncthreads();

    int cur = 0;
    const int tstep = dir ? -1 : 1;
    int t = dir ? (NT - 1) : 0;
    for (int tt = 0; tt < NT; ++tt, t += tstep) {
        // issue gx loads early (q==0 waves only); latency hides under dots
        float gxr = 0.f, gxz = 0.f, gxn = 0.f;
        if (q == 0) {
            const _Float16* gxt = gxp + (size_t)t * G3;
            gxr = (float)gxt[j];
            gxz = (float)gxt[256 + j];
            gxn = (float)gxt[512 + j];
        }

        // partial dots over this thread's 32 k2 values
        float ar = 0.f, az = 0.f, an = 0.f;
        const u32x4* hp = hl[cur] + q * 8;
        #pragma unroll
        for (int k4 = 0; k4 < 8; ++k4) {
            u32x4 hv = hp[k4];   // wave-uniform address -> LDS broadcast
            #pragma unroll
            for (int e = 0; e < 4; ++e) {
                int k = k4 * 4 + e;
                ar = fdot2f(hv[e], wr[k], ar);
                az = fdot2f(hv[e], wz[k], az);
                an = fdot2f(hv[e], wn[k], an);
            }
        }
        psum[q][j]       = ar;
        psum[q][256 + j] = az;
        psum[q][512 + j] = an;

        asm volatile("s_waitcnt lgkmcnt(0)" ::: "memory");
        __builtin_amdgcn_s_barrier();
        asm volatile("" ::: "memory");

        if (q == 0) {
            float arT = psum[0][j]       + psum[1][j]       + psum[2][j]       + psum[3][j];
            float azT = psum[0][256 + j] + psum[1][256 + j] + psum[2][256 + j] + psum[3][256 + j];
            float anT = psum[0][512 + j] + psum[1][512 + j] + psum[2][512 + j] + psum[3][512 + j];

            float r = sigmoidf_fast(gxr + arT + bhr);
            float z = sigmoidf_fast(gxz + azT + bhz);
            float n = tanhf_fast(gxn + r * (anT + bhn));
            h = z * h + (1.0f - z) * n;

            outp[(size_t)t * 512] = h;
            ((_Float16*)hl[cur ^ 1])[j] = (_Float16)h;
        }

        asm volatile("s_waitcnt lgkmcnt(0)" ::: "memory");
        __builtin_amdgcn_s_barrier();
        asm volatile("" ::: "memory");
        cur ^= 1;
    }

    if (q == 0) {
        float* hout = out + (size_t)NB * NT * 512 + dir * (NB * NH);
        hout[b * NH + j] = h;
    }
}

extern "C" void kernel_launch(void* const* d_in, const int* in_sizes, int n_in,
                              void* d_out, int out_size, void* d_ws, size_t ws_size,
                              hipStream_t stream) {
    const float* x      = (const float*)d_in[0];
    const float* wih_fw = (const float*)d_in[1];
    const float* whh_fw = (const float*)d_in[2];
    const float* bih_fw = (const float*)d_in[3];
    const float* bhh_fw = (const float*)d_in[4];
    const float* wih_bw = (const float*)d_in[5];
    const float* whh_bw = (const float*)d_in[6];
    const float* bih_bw = (const float*)d_in[7];
    const float* bhh_bw = (const float*)d_in[8];
    float* out = (float*)d_out;

    char* ws = (char*)d_ws;
    _Float16* gx = (_Float16*)ws;                      // 2*65536*768*2 = 201,326,592 B
    u32* wihp = (u32*)(ws + 201326592);                // 786,432 B
    u32* whhp = (u32*)(ws + 202113024);                // 786,432 B

    pack_w<<<768, 256, 0, stream>>>(wih_fw, wih_bw, wihp);
    pack_w<<<768, 256, 0, stream>>>(whh_fw, whh_bw, whhp);
    gemm_gx<<<dim3(4096, 2), 256, 0, stream>>>(x, wihp, bih_fw, bih_bw, gx);
    gru_rec<<<dim3(NB, 2), 1024, 0, stream>>>(gx, whhp, bhh_fw, bhh_bw, out);
}